// Round 9
// baseline (1033.054 us; speedup 1.0000x reference)
//
#include <hip/hip_runtime.h>

// ---------------------------------------------------------------------------
// Cascade MLP, MI355X. fp16 hi/lo split GEMMs (3 passes, fp32 accum) on
// v_mfma_f32_32x32x16_f16.
// Round-9 restructure: FRAGMENT-MAJOR layouts. All weight/h images are stored
// as raw MFMA fragments (64 lanes x 16B = 1KB per fragment), so every
// ds_read_b128 is lane-linear -> ZERO bank conflicts (round-5 profile showed
// 2.8e7 conflict cycles: every read was 8-way under the old row-major+pad
// layout). 32x32x16 halves LDS bytes per FLOP vs 16x16x32.
// Bias is folded into the GEMM: h feature 127 == 1.0, weight row k=127 holds
// the bias (identity column keeps it alive through layers); head pad classes
// get bias -60000 so they never win the max.
//   A-frag (weights): lane l -> feature row l&31, k-octet l>>5.
//   B-frag (x / h):   lane l -> batch-row  l&31, k-octet l>>5.
//   C/D (verified):   col = lane&31 (batch-row),
//                     row = (reg&3)+8*(reg>>2)+4*(lane>>5) (feature).
// p1: x @ W1 -> h1 frags in ws. 1024 blk x 512 thr, LDS 48KB, 2 blocks/CU.
// p2: 14-layer cascade + 3 heads + select. 512 blk x 512 thr, h in LDS 64KB,
//     3-buf counted-vmcnt ring, pure GEMM inner loop.
// ---------------------------------------------------------------------------

typedef __fp16 h2   __attribute__((ext_vector_type(2)));
typedef __fp16 h8v  __attribute__((ext_vector_type(8)));
typedef float  f4v  __attribute__((ext_vector_type(4)));
typedef float  f16v __attribute__((ext_vector_type(16)));

#define CHUNK 16384   // one staged unit: 16 fragments x 1KB (BK=32 x 128 feat)

static constexpr unsigned OFF_W1  = 0;                       // 96 chunks
static constexpr unsigned OFF_WH  = 96u * CHUNK;             // 1572864, 56 chunks
static constexpr unsigned OFF_WO  = OFF_WH + 56u * CHUNK;    // 2490368, 3 chunks
static constexpr unsigned OFF_BIN = OFF_WO + 3u * CHUNK;     // 2539520, 128 f32
static constexpr unsigned OFF_H1  = OFF_BIN + 512;           // 2540032, 512 x 64KB

__device__ __forceinline__ unsigned bc2(h2 v) { return __builtin_bit_cast(unsigned, v); }

__device__ __forceinline__ f4v ntld4(const float* p) {
  return __builtin_nontemporal_load((const f4v*)p);
}

__device__ __forceinline__ void lds_cp16(const char* g, char* l) {
  __builtin_amdgcn_global_load_lds(
      (const __attribute__((address_space(1))) void*)g,
      (__attribute__((address_space(3))) void*)l, 16, 0, 0);
}

// stage one 16KB chunk with 512 threads: 2 x 16B per thread
__device__ __forceinline__ void stage2(const char* g, char* l, int tid) {
  lds_cp16(g + tid * 16, l + tid * 16);
  lds_cp16(g + 8192 + tid * 16, l + 8192 + tid * 16);
}

// 8 fp32 (two f4v) -> hi/lo h8v fragments (element order e0..e7)
__device__ __forceinline__ void cvt8(f4v a, f4v b, h8v& hi, h8v& lo) {
  h2 h0 = __builtin_amdgcn_cvt_pkrtz(a[0], a[1]);
  h2 h1 = __builtin_amdgcn_cvt_pkrtz(a[2], a[3]);
  h2 h2_ = __builtin_amdgcn_cvt_pkrtz(b[0], b[1]);
  h2 h3 = __builtin_amdgcn_cvt_pkrtz(b[2], b[3]);
  h2 l0 = __builtin_amdgcn_cvt_pkrtz(a[0] - (float)h0[0], a[1] - (float)h0[1]);
  h2 l1 = __builtin_amdgcn_cvt_pkrtz(a[2] - (float)h1[0], a[3] - (float)h1[1]);
  h2 l2 = __builtin_amdgcn_cvt_pkrtz(b[0] - (float)h2_[0], b[1] - (float)h2_[1]);
  h2 l3 = __builtin_amdgcn_cvt_pkrtz(b[2] - (float)h3[0], b[3] - (float)h3[1]);
  hi = h8v{h0[0], h0[1], h1[0], h1[1], h2_[0], h2_[1], h3[0], h3[1]};
  lo = h8v{l0[0], l0[1], l1[0], l1[1], l2[0], l2[1], l3[0], l3[1]};
}

// relu'd f4v -> hi 8B + lo 8B
__device__ __forceinline__ void split4s(f4v v, uint2& hi, uint2& lo) {
  h2 a = __builtin_amdgcn_cvt_pkrtz(v[0], v[1]);
  h2 b = __builtin_amdgcn_cvt_pkrtz(v[2], v[3]);
  h2 c = __builtin_amdgcn_cvt_pkrtz(v[0] - (float)a[0], v[1] - (float)a[1]);
  h2 d = __builtin_amdgcn_cvt_pkrtz(v[2] - (float)b[0], v[3] - (float)b[1]);
  hi = make_uint2(bc2(a), bc2(b));
  lo = make_uint2(bc2(c), bc2(d));
}

__device__ __forceinline__ void split8w(const float* f, uint4& hi, uint4& lo) {
  h2 h0 = __builtin_amdgcn_cvt_pkrtz(f[0], f[1]);
  h2 h1 = __builtin_amdgcn_cvt_pkrtz(f[2], f[3]);
  h2 h2_ = __builtin_amdgcn_cvt_pkrtz(f[4], f[5]);
  h2 h3 = __builtin_amdgcn_cvt_pkrtz(f[6], f[7]);
  h2 l0 = __builtin_amdgcn_cvt_pkrtz(f[0] - (float)h0[0], f[1] - (float)h0[1]);
  h2 l1 = __builtin_amdgcn_cvt_pkrtz(f[2] - (float)h1[0], f[3] - (float)h1[1]);
  h2 l2 = __builtin_amdgcn_cvt_pkrtz(f[4] - (float)h2_[0], f[5] - (float)h2_[1]);
  h2 l3 = __builtin_amdgcn_cvt_pkrtz(f[6] - (float)h3[0], f[7] - (float)h3[1]);
  hi = make_uint4(bc2(h0), bc2(h1), bc2(h2_), bc2(h3));
  lo = make_uint4(bc2(l0), bc2(l1), bc2(l2), bc2(l3));
}

// flat items: L0-3=0..15, head0=16, L4-8=17..36, head1=37, L9-13=38..57, head2=58
__device__ __forceinline__ unsigned item_off(int it) {
  if (it >= 58) return OFF_WO + 2u * CHUNK;   // 58 + dummy tails
  if (it == 16) return OFF_WO;
  if (it == 37) return OFF_WO + CHUNK;
  int j = it - (it > 16 ? 1 : 0) - (it > 37 ? 1 : 0);
  return OFF_WH + (unsigned)j * CHUNK;
}

// ---------------------------------------------------------------------------
// prep: build fragment-major images. thread group (64 lanes) = one fragment
// pair (hi+lo).
// ---------------------------------------------------------------------------
__global__ __launch_bounds__(256) void prep_k(
    const float* __restrict__ w_in, const float* __restrict__ b_in,
    const float* __restrict__ w_hid, const float* __restrict__ b_hid,
    const float* __restrict__ w_out, const float* __restrict__ b_out,
    char* __restrict__ ws) {
  int idx = blockIdx.x * 256 + threadIdx.x;
  int lane = idx & 63;
  int grp = idx >> 6;
  float f[8];
  uint4 hi, lo;
  if (grp < 768) {  // W1: c(96) x ft(4) x j(2)
    int j = grp & 1, ft = (grp >> 1) & 3, c = grp >> 3;
    int feat = ft * 32 + (lane & 31);
    int k0 = c * 32 + j * 16 + (lane >> 5) * 8;
#pragma unroll
    for (int e = 0; e < 8; ++e)
      f[e] = (feat < 100) ? w_in[(size_t)(k0 + e) * 100 + feat] : 0.f;
    split8w(f, hi, lo);
    char* dst = ws + OFF_W1 + (size_t)c * CHUNK + (size_t)((ft * 2 + j) * 2) * 1024 + lane * 16;
    *(uint4*)dst = hi;
    *(uint4*)(dst + 1024) = lo;
    return;
  }
  grp -= 768;
  if (grp < 448) {  // WH: ch(56 = L*4+s) x ft(4) x j(2); bias row at k=127
    int j = grp & 1, ft = (grp >> 1) & 3, ch = grp >> 3;
    int L = ch >> 2, s = ch & 3;
    int feat = ft * 32 + (lane & 31);
    int k0 = s * 32 + j * 16 + (lane >> 5) * 8;
#pragma unroll
    for (int e = 0; e < 8; ++e) {
      int k = k0 + e;
      float v;
      if (k < 100 && feat < 100)  v = w_hid[(size_t)L * 10000 + k * 100 + feat];
      else if (k == 127)          v = (feat < 100) ? b_hid[L * 100 + feat]
                                                   : (feat == 127 ? 1.f : 0.f);
      else                        v = 0.f;
      f[e] = v;
    }
    split8w(f, hi, lo);
    char* dst = ws + OFF_WH + (size_t)ch * CHUNK + (size_t)((ft * 2 + j) * 2) * 1024 + lane * 16;
    *(uint4*)dst = hi;
    *(uint4*)(dst + 1024) = lo;
    return;
  }
  grp -= 448;
  if (grp < 24) {  // WO: st(3) x kblk(8); bias row k=127, pad classes -60000
    int kb = grp & 7, st = grp >> 3;
    int cls = lane & 31;
    int k0 = kb * 16 + (lane >> 5) * 8;
#pragma unroll
    for (int e = 0; e < 8; ++e) {
      int k = k0 + e;
      float v;
      if (cls < 10 && k < 100) v = w_out[(size_t)st * 1000 + k * 10 + cls];
      else if (k == 127)       v = (cls < 10) ? b_out[st * 10 + cls] : -60000.f;
      else                     v = 0.f;
      f[e] = v;
    }
    split8w(f, hi, lo);
    char* dst = ws + OFF_WO + (size_t)st * CHUNK + (size_t)(kb * 2) * 1024 + lane * 16;
    *(uint4*)dst = hi;
    *(uint4*)(dst + 1024) = lo;
    return;
  }
  grp -= 24;
  if (grp < 2) {  // BIN: p1 epilogue bias (128 f32), bin[127] = 1.0
    int i = grp * 64 + lane;
    ((float*)(ws + OFF_BIN))[i] = (i < 100) ? b_in[i] : (i == 127 ? 1.f : 0.f);
  }
}

// ---------------------------------------------------------------------------
// p1: h1 = relu(x @ w_in + b_in) -> fragment-major h image in ws.
// 1024 blocks x 512 thr; wave = 32 feat (ft = wid>>1) x 32 rows (nc = wid&1).
// ---------------------------------------------------------------------------
#define P1_SMEM (3 * CHUNK)  // 49152 -> 2 blocks/CU (with VGPR <= 128)

__global__ __launch_bounds__(512, 4) void p1_k(const float* __restrict__ x,
                                               char* __restrict__ ws) {
  extern __shared__ __align__(16) char sm[];
  const int tid = threadIdx.x;
  const int lane = tid & 63, wid = tid >> 6;
  const int ft = wid >> 1, nc = wid & 1;
  const int l31 = lane & 31, gg = lane >> 5;
  const int tile = blockIdx.x;  // 64 rows
  const char* w1g = ws + OFF_W1;
  const float* xr = x + (size_t)(tile * 64 + nc * 32 + l31) * 3072;

  f4v xaP[4], xaQ[4];
  // prologue FIFO: c0(2), x0(4), c1(2), x1(4)
  stage2(w1g, sm, tid);
  __builtin_amdgcn_sched_barrier(0);
  {
    const int o = gg * 8;
    xaP[0] = ntld4(xr + o);      xaP[1] = ntld4(xr + o + 4);
    xaP[2] = ntld4(xr + o + 16); xaP[3] = ntld4(xr + o + 20);
  }
  __builtin_amdgcn_sched_barrier(0);
  stage2(w1g + CHUNK, sm + CHUNK, tid);
  __builtin_amdgcn_sched_barrier(0);
  {
    const int o = 32 + gg * 8;
    xaQ[0] = ntld4(xr + o);      xaQ[1] = ntld4(xr + o + 4);
    xaQ[2] = ntld4(xr + o + 16); xaQ[3] = ntld4(xr + o + 20);
  }
  __builtin_amdgcn_sched_barrier(0);

  f16v acc = {};
  const int abase = ft * 4096 + lane * 16;

  auto step = [&](int s, f4v (&xa)[4]) {
    if (s == 95) asm volatile("s_waitcnt vmcnt(0)" ::: "memory");
    else         asm volatile("s_waitcnt vmcnt(6)" ::: "memory");
    __builtin_amdgcn_s_barrier();
    asm volatile("" ::: "memory");

    h8v bh0, bl0, bh1, bl1;
    cvt8(xa[0], xa[1], bh0, bl0);  // j = 0 (k 0..15 of this step)
    cvt8(xa[2], xa[3], bh1, bl1);  // j = 1 (k 16..31)
    if (s + 2 < 96) {
      stage2(w1g + (size_t)(s + 2) * CHUNK, sm + ((s + 2) % 3) * CHUNK, tid);
      const int o = (s + 2) * 32 + gg * 8;
      xa[0] = ntld4(xr + o);      xa[1] = ntld4(xr + o + 4);
      xa[2] = ntld4(xr + o + 16); xa[3] = ntld4(xr + o + 20);
    }
    __builtin_amdgcn_sched_barrier(0);

    const char* ab = sm + (s % 3) * CHUNK + abase;
    h8v ah0 = *(const h8v*)(ab);
    h8v al0 = *(const h8v*)(ab + 1024);
    h8v ah1 = *(const h8v*)(ab + 2048);
    h8v al1 = *(const h8v*)(ab + 3072);
    acc = __builtin_amdgcn_mfma_f32_32x32x16_f16(ah0, bh0, acc, 0, 0, 0);
    acc = __builtin_amdgcn_mfma_f32_32x32x16_f16(ah0, bl0, acc, 0, 0, 0);
    acc = __builtin_amdgcn_mfma_f32_32x32x16_f16(al0, bh0, acc, 0, 0, 0);
    acc = __builtin_amdgcn_mfma_f32_32x32x16_f16(ah1, bh1, acc, 0, 0, 0);
    acc = __builtin_amdgcn_mfma_f32_32x32x16_f16(ah1, bl1, acc, 0, 0, 0);
    acc = __builtin_amdgcn_mfma_f32_32x32x16_f16(al1, bh1, acc, 0, 0, 0);
  };

#pragma unroll 1
  for (int s2 = 0; s2 < 96; s2 += 2) {
    step(s2, xaP);
    step(s2 + 1, xaQ);
  }

  // epilogue: FIFO empty. bias + relu + split -> global h frags.
  const float* bp = (const float*)(ws + OFF_BIN) + ft * 32 + gg * 4;
  const int rt = (tile & 1) * 2 + nc;                       // row-tile in 128-row p2 tile
  char* hb = ws + OFF_H1 + (size_t)(tile >> 1) * 65536;
#pragma unroll
  for (int q = 0; q < 4; ++q) {
    f4v bi = *(const f4v*)(bp + q * 8);
    f4v v = f4v{acc[4 * q], acc[4 * q + 1], acc[4 * q + 2], acc[4 * q + 3]} + bi;
    v[0] = fmaxf(v[0], 0.f); v[1] = fmaxf(v[1], 0.f);
    v[2] = fmaxf(v[2], 0.f); v[3] = fmaxf(v[3], 0.f);
    uint2 hi, lo;
    split4s(v, hi, lo);
    const int kblk = ft * 2 + (q >> 1);
    char* dst = hb + (size_t)((rt * 8 + kblk) * 2) * 1024 + ((q & 1) * 32 + l31) * 16 + gg * 8;
    *(uint2*)dst = hi;
    *(uint2*)(dst + 1024) = lo;
  }
}

// ---------------------------------------------------------------------------
// p2: cascade + heads + early-exit select. 512 blocks x 512 thr.
// wave = 64 feat (mr = wid&1, fi 0..1) x 32 rows (rt = wid>>1).
// ---------------------------------------------------------------------------
#define P2_SMEM (65536 + 3 * CHUNK)  // 114688

__global__ __launch_bounds__(512, 2) void p2_k(char* __restrict__ ws,
                                               float* __restrict__ out) {
  extern __shared__ __align__(16) char sm[];
  char* hsm = sm;             // h frags, 64KB
  char* wsm = sm + 65536;     // 3 chunk bufs
  const int tid = threadIdx.x;
  const int lane = tid & 63, wid = tid >> 6;
  const int mr = wid & 1, rt = wid >> 1;
  const int l31 = lane & 31, gg = lane >> 5;
  const int tile = blockIdx.x;

  {  // prologue DMA: h tile (8 loads) + items 0,1 (FIFO: h8, c0 2, c1 2)
    const char* hg = ws + OFF_H1 + (size_t)tile * 65536;
#pragma unroll
    for (int i = 0; i < 8; ++i)
      lds_cp16(hg + i * 8192 + tid * 16, hsm + i * 8192 + tid * 16);
    __builtin_amdgcn_sched_barrier(0);
    stage2(ws + item_off(0), wsm, tid);
    stage2(ws + item_off(1), wsm + CHUNK, tid);
  }

  const f16v z16 = {};
  f16v a0 = {}, a1 = {};
  float s0[6], s1[6], s2[6];
  bool c0 = false, c1 = false;

  // ring: wait stage(i) done (leaves stage(i+1)) -> barrier -> stage(i+2).
  // buf (i+2)%3 == (i-1)%3: its readers finished before this barrier.
  auto ring_top = [&](int i) {
    asm volatile("s_waitcnt vmcnt(2)" ::: "memory");
    __builtin_amdgcn_s_barrier();
    asm volatile("" ::: "memory");
    stage2(ws + item_off(i + 2), wsm + ((i + 2) % 3) * CHUNK, tid);
  };

  auto hidden = [&](int base) {
#pragma unroll
    for (int ss = 0; ss < 4; ++ss) {
      ring_top(base + ss);
      const char* wb = wsm + ((base + ss) % 3) * CHUNK + lane * 16;
      const char* hbp = hsm + rt * 16384 + ss * 4096 + lane * 16;
      h8v bh0 = *(const h8v*)(hbp);
      h8v bl0 = *(const h8v*)(hbp + 1024);
      h8v bh1 = *(const h8v*)(hbp + 2048);
      h8v bl1 = *(const h8v*)(hbp + 3072);
      const char* ab0 = wb + (mr * 2) * 4096;
      const char* ab1 = ab0 + 4096;
      h8v ah, al;
      ah = *(const h8v*)(ab0);        al = *(const h8v*)(ab0 + 1024);
      a0 = __builtin_amdgcn_mfma_f32_32x32x16_f16(ah, bh0, a0, 0, 0, 0);
      a0 = __builtin_amdgcn_mfma_f32_32x32x16_f16(ah, bl0, a0, 0, 0, 0);
      a0 = __builtin_amdgcn_mfma_f32_32x32x16_f16(al, bh0, a0, 0, 0, 0);
      ah = *(const h8v*)(ab0 + 2048); al = *(const h8v*)(ab0 + 3072);
      a0 = __builtin_amdgcn_mfma_f32_32x32x16_f16(ah, bh1, a0, 0, 0, 0);
      a0 = __builtin_amdgcn_mfma_f32_32x32x16_f16(ah, bl1, a0, 0, 0, 0);
      a0 = __builtin_amdgcn_mfma_f32_32x32x16_f16(al, bh1, a0, 0, 0, 0);
      ah = *(const h8v*)(ab1);        al = *(const h8v*)(ab1 + 1024);
      a1 = __builtin_amdgcn_mfma_f32_32x32x16_f16(ah, bh0, a1, 0, 0, 0);
      a1 = __builtin_amdgcn_mfma_f32_32x32x16_f16(ah, bl0, a1, 0, 0, 0);
      a1 = __builtin_amdgcn_mfma_f32_32x32x16_f16(al, bh0, a1, 0, 0, 0);
      ah = *(const h8v*)(ab1 + 2048); al = *(const h8v*)(ab1 + 3072);
      a1 = __builtin_amdgcn_mfma_f32_32x32x16_f16(ah, bh1, a1, 0, 0, 0);
      a1 = __builtin_amdgcn_mfma_f32_32x32x16_f16(ah, bl1, a1, 0, 0, 0);
      a1 = __builtin_amdgcn_mfma_f32_32x32x16_f16(al, bh1, a1, 0, 0, 0);
    }
    // epilogue: all reads of old h done -> relu (bias folded) -> overwrite
    __builtin_amdgcn_s_barrier();
    asm volatile("" ::: "memory");
#pragma unroll
    for (int fi = 0; fi < 2; ++fi) {
      const int ftb = mr * 2 + fi;
#pragma unroll
      for (int q = 0; q < 4; ++q) {
        f4v v = fi ? f4v{a1[4 * q], a1[4 * q + 1], a1[4 * q + 2], a1[4 * q + 3]}
                   : f4v{a0[4 * q], a0[4 * q + 1], a0[4 * q + 2], a0[4 * q + 3]};
        v[0] = fmaxf(v[0], 0.f); v[1] = fmaxf(v[1], 0.f);
        v[2] = fmaxf(v[2], 0.f); v[3] = fmaxf(v[3], 0.f);
        uint2 hi, lo;
        split4s(v, hi, lo);
        const int kblk = ftb * 2 + (q >> 1);
        char* dst = hsm + (size_t)((rt * 8 + kblk) * 2) * 1024 + ((q & 1) * 32 + l31) * 16 + gg * 8;
        *(uint2*)dst = hi;
        *(uint2*)(dst + 1024) = lo;
      }
    }
    asm volatile("s_waitcnt lgkmcnt(0)" ::: "memory");
    __builtin_amdgcn_s_barrier();
    asm volatile("" ::: "memory");
    a0 = z16;
    a1 = z16;
  };

  auto wstage = [&](int i, float (&sv)[6], bool* cb) {
    ring_top(i);
    const char* wb = wsm + (i % 3) * CHUNK + lane * 16;
    if (mr == 0) {  // 4 rt-waves compute the head (wave-uniform branch)
      f16v oa = {};
#pragma unroll
      for (int kb = 0; kb < 8; ++kb) {
        h8v ah = *(const h8v*)(wb + kb * 2048);
        h8v al = *(const h8v*)(wb + kb * 2048 + 1024);
        const char* hbp = hsm + rt * 16384 + kb * 2048 + lane * 16;
        h8v bh = *(const h8v*)(hbp);
        h8v bl = *(const h8v*)(hbp + 1024);
        oa = __builtin_amdgcn_mfma_f32_32x32x16_f16(ah, bh, oa, 0, 0, 0);
        oa = __builtin_amdgcn_mfma_f32_32x32x16_f16(ah, bl, oa, 0, 0, 0);
        oa = __builtin_amdgcn_mfma_f32_32x32x16_f16(al, bh, oa, 0, 0, 0);
      }
      float m = oa[0];
#pragma unroll
      for (int r = 1; r < 16; ++r) m = fmaxf(m, oa[r]);  // pads = -60000
      m = fmaxf(m, __shfl_xor(m, 32, 64));
      if (cb) *cb = (m > 0.5f);
      sv[0] = oa[0]; sv[1] = oa[1]; sv[2] = oa[2];
      sv[3] = oa[3]; sv[4] = oa[4]; sv[5] = oa[5];
    }
  };

  hidden(0); hidden(4); hidden(8); hidden(12);
  wstage(16, s0, &c0);
  hidden(17); hidden(21); hidden(25); hidden(29); hidden(33);
  wstage(37, s1, &c1);
  hidden(38); hidden(42); hidden(46); hidden(50); hidden(54);
  wstage(58, s2, nullptr);

  if (mr == 0) {  // early-exit select + store
    float r[6];
#pragma unroll
    for (int j = 0; j < 6; ++j) r[j] = c0 ? s0[j] : (c1 ? s1[j] : s2[j]);
    float* dp = out + (size_t)(tile * 128 + rt * 32 + l31) * 10;
    if (gg == 0) {  // classes 0-3, 8-9
      *(float2*)(dp)     = make_float2(r[0], r[1]);
      *(float2*)(dp + 2) = make_float2(r[2], r[3]);
      *(float2*)(dp + 8) = make_float2(r[4], r[5]);
    } else {        // classes 4-7
      *(float2*)(dp + 4) = make_float2(r[0], r[1]);
      *(float2*)(dp + 6) = make_float2(r[2], r[3]);
    }
  }
}

// ---------------------------------------------------------------------------
extern "C" void kernel_launch(void* const* d_in, const int* in_sizes, int n_in,
                              void* d_out, int out_size, void* d_ws, size_t ws_size,
                              hipStream_t stream) {
  (void)in_sizes; (void)n_in; (void)out_size; (void)ws_size;
  const float* x     = (const float*)d_in[0];
  const float* w_in  = (const float*)d_in[1];
  const float* b_in  = (const float*)d_in[2];
  const float* w_hid = (const float*)d_in[3];
  const float* b_hid = (const float*)d_in[4];
  const float* w_out = (const float*)d_in[5];
  const float* b_out = (const float*)d_in[6];
  float* out = (float*)d_out;
  char* ws = (char*)d_ws;

  (void)hipFuncSetAttribute((const void*)p1_k,
                            hipFuncAttributeMaxDynamicSharedMemorySize, P1_SMEM);
  (void)hipFuncSetAttribute((const void*)p2_k,
                            hipFuncAttributeMaxDynamicSharedMemorySize, P2_SMEM);

  prep_k<<<311, 256, 0, stream>>>(w_in, b_in, w_hid, b_hid, w_out, b_out, ws);
  p1_k<<<1024, 512, P1_SMEM, stream>>>(x, ws);
  p2_k<<<512, 512, P2_SMEM, stream>>>(ws, out);
}

// Round 10
// 328.205 us; speedup vs baseline: 3.1476x; 3.1476x over previous
//
#include <hip/hip_runtime.h>

// ---------------------------------------------------------------------------
// Cascade MLP, MI355X. fp16 hi/lo split GEMMs (3 passes, fp32 accum).
// FRAGMENT-MAJOR layouts everywhere: weight/h images are raw MFMA fragments
// (64 lanes x 16B = 1KB), every ds_read_b128 lane-linear -> zero conflicts
// (verified round 9: SQ_LDS_BANK_CONFLICT 2.8e7 -> 0).
// Round-10: p1 rebuilt on 16x16x32 with a CUSTOM K-PERMUTATION
// kappa(g,e) = e<4 ? g*4+e : 16+g*4+(e-4), applied identically to the W1
// image (prep) and the x loads (cvt8 of two dense f4v) -- so each x-load
// instruction covers 16 rows x one FULL 64B line (round-9's 32x32 pattern
// was 2x requests/byte + 4x ft-wave redundancy = 8x line-requests -> 940us).
// Wave = 16 rows x 128 feats (no x redundancy); 3-step x prefetch.
// p2 (32x32 fragment-major cascade, bias folded via h[127]=1): unchanged.
// ---------------------------------------------------------------------------

typedef __fp16 h2   __attribute__((ext_vector_type(2)));
typedef __fp16 h8v  __attribute__((ext_vector_type(8)));
typedef float  f4v  __attribute__((ext_vector_type(4)));
typedef float  f16v __attribute__((ext_vector_type(16)));

#define CHUNK 16384   // one staged unit: 16 fragments x 1KB

static constexpr unsigned OFF_W1  = 0;                       // 96 chunks
static constexpr unsigned OFF_WH  = 96u * CHUNK;             // 1572864, 56 chunks
static constexpr unsigned OFF_WO  = OFF_WH + 56u * CHUNK;    // 2490368, 3 chunks
static constexpr unsigned OFF_BIN = OFF_WO + 3u * CHUNK;     // 2539520, 128 f32
static constexpr unsigned OFF_H1  = OFF_BIN + 512;           // 2540032, 512 x 64KB

__device__ __forceinline__ unsigned bc2(h2 v) { return __builtin_bit_cast(unsigned, v); }

__device__ __forceinline__ f4v ntld4(const float* p) {
  return __builtin_nontemporal_load((const f4v*)p);
}

__device__ __forceinline__ void lds_cp16(const char* g, char* l) {
  __builtin_amdgcn_global_load_lds(
      (const __attribute__((address_space(1))) void*)g,
      (__attribute__((address_space(3))) void*)l, 16, 0, 0);
}

// stage one 16KB chunk with 512 threads: 2 x 16B per thread
__device__ __forceinline__ void stage2(const char* g, char* l, int tid) {
  lds_cp16(g + tid * 16, l + tid * 16);
  lds_cp16(g + 8192 + tid * 16, l + 8192 + tid * 16);
}

// 8 fp32 (two f4v) -> hi/lo h8v fragments (element order a0..a3, b0..b3)
__device__ __forceinline__ void cvt8(f4v a, f4v b, h8v& hi, h8v& lo) {
  h2 h0 = __builtin_amdgcn_cvt_pkrtz(a[0], a[1]);
  h2 h1 = __builtin_amdgcn_cvt_pkrtz(a[2], a[3]);
  h2 h2_ = __builtin_amdgcn_cvt_pkrtz(b[0], b[1]);
  h2 h3 = __builtin_amdgcn_cvt_pkrtz(b[2], b[3]);
  h2 l0 = __builtin_amdgcn_cvt_pkrtz(a[0] - (float)h0[0], a[1] - (float)h0[1]);
  h2 l1 = __builtin_amdgcn_cvt_pkrtz(a[2] - (float)h1[0], a[3] - (float)h1[1]);
  h2 l2 = __builtin_amdgcn_cvt_pkrtz(b[0] - (float)h2_[0], b[1] - (float)h2_[1]);
  h2 l3 = __builtin_amdgcn_cvt_pkrtz(b[2] - (float)h3[0], b[3] - (float)h3[1]);
  hi = h8v{h0[0], h0[1], h1[0], h1[1], h2_[0], h2_[1], h3[0], h3[1]};
  lo = h8v{l0[0], l0[1], l1[0], l1[1], l2[0], l2[1], l3[0], l3[1]};
}

// relu'd f4v -> hi 8B + lo 8B
__device__ __forceinline__ void split4s(f4v v, uint2& hi, uint2& lo) {
  h2 a = __builtin_amdgcn_cvt_pkrtz(v[0], v[1]);
  h2 b = __builtin_amdgcn_cvt_pkrtz(v[2], v[3]);
  h2 c = __builtin_amdgcn_cvt_pkrtz(v[0] - (float)a[0], v[1] - (float)a[1]);
  h2 d = __builtin_amdgcn_cvt_pkrtz(v[2] - (float)b[0], v[3] - (float)b[1]);
  hi = make_uint2(bc2(a), bc2(b));
  lo = make_uint2(bc2(c), bc2(d));
}

__device__ __forceinline__ void split8w(const float* f, uint4& hi, uint4& lo) {
  h2 h0 = __builtin_amdgcn_cvt_pkrtz(f[0], f[1]);
  h2 h1 = __builtin_amdgcn_cvt_pkrtz(f[2], f[3]);
  h2 h2_ = __builtin_amdgcn_cvt_pkrtz(f[4], f[5]);
  h2 h3 = __builtin_amdgcn_cvt_pkrtz(f[6], f[7]);
  h2 l0 = __builtin_amdgcn_cvt_pkrtz(f[0] - (float)h0[0], f[1] - (float)h0[1]);
  h2 l1 = __builtin_amdgcn_cvt_pkrtz(f[2] - (float)h1[0], f[3] - (float)h1[1]);
  h2 l2 = __builtin_amdgcn_cvt_pkrtz(f[4] - (float)h2_[0], f[5] - (float)h2_[1]);
  h2 l3 = __builtin_amdgcn_cvt_pkrtz(f[6] - (float)h3[0], f[7] - (float)h3[1]);
  hi = make_uint4(bc2(h0), bc2(h1), bc2(h2_), bc2(h3));
  lo = make_uint4(bc2(l0), bc2(l1), bc2(l2), bc2(l3));
}

// flat items: L0-3=0..15, head0=16, L4-8=17..36, head1=37, L9-13=38..57, head2=58
__device__ __forceinline__ unsigned item_off(int it) {
  if (it >= 58) return OFF_WO + 2u * CHUNK;   // 58 + dummy tails
  if (it == 16) return OFF_WO;
  if (it == 37) return OFF_WO + CHUNK;
  int j = it - (it > 16 ? 1 : 0) - (it > 37 ? 1 : 0);
  return OFF_WH + (unsigned)j * CHUNK;
}

// ---------------------------------------------------------------------------
// prep: fragment-major images. 64-lane group = one fragment pair (hi+lo).
// ---------------------------------------------------------------------------
__global__ __launch_bounds__(256) void prep_k(
    const float* __restrict__ w_in, const float* __restrict__ b_in,
    const float* __restrict__ w_hid, const float* __restrict__ b_hid,
    const float* __restrict__ w_out, const float* __restrict__ b_out,
    char* __restrict__ ws) {
  int idx = blockIdx.x * 256 + threadIdx.x;
  int lane = idx & 63;
  int grp = idx >> 6;
  float f[8];
  uint4 hi, lo;
  if (grp < 768) {  // W1: c(96) x mf(8) 16x16x32 A-frags, CUSTOM k-perm
    int mf = grp & 7, c = grp >> 3;
    int feat = mf * 16 + (lane & 15);
    int g = lane >> 4;
    int kb = c * 32 + g * 4;
#pragma unroll
    for (int e = 0; e < 8; ++e) {
      int k = kb + (e < 4 ? e : 12 + e);   // kappa(g,e): e>=4 -> +16
      f[e] = (feat < 100) ? w_in[(size_t)k * 100 + feat] : 0.f;
    }
    split8w(f, hi, lo);
    char* dst = ws + OFF_W1 + (size_t)c * CHUNK + (size_t)mf * 2048 + lane * 16;
    *(uint4*)dst = hi;
    *(uint4*)(dst + 1024) = lo;
    return;
  }
  grp -= 768;
  if (grp < 448) {  // WH: ch(56 = L*4+s) x ft(4) x j(2), 32x32 frags; bias @k=127
    int j = grp & 1, ft = (grp >> 1) & 3, ch = grp >> 3;
    int L = ch >> 2, s = ch & 3;
    int feat = ft * 32 + (lane & 31);
    int k0 = s * 32 + j * 16 + (lane >> 5) * 8;
#pragma unroll
    for (int e = 0; e < 8; ++e) {
      int k = k0 + e;
      float v;
      if (k < 100 && feat < 100)  v = w_hid[(size_t)L * 10000 + k * 100 + feat];
      else if (k == 127)          v = (feat < 100) ? b_hid[L * 100 + feat]
                                                   : (feat == 127 ? 1.f : 0.f);
      else                        v = 0.f;
      f[e] = v;
    }
    split8w(f, hi, lo);
    char* dst = ws + OFF_WH + (size_t)ch * CHUNK + (size_t)((ft * 2 + j) * 2) * 1024 + lane * 16;
    *(uint4*)dst = hi;
    *(uint4*)(dst + 1024) = lo;
    return;
  }
  grp -= 448;
  if (grp < 24) {  // WO: st(3) x kblk(8); bias row k=127, pad classes -60000
    int kb = grp & 7, st = grp >> 3;
    int cls = lane & 31;
    int k0 = kb * 16 + (lane >> 5) * 8;
#pragma unroll
    for (int e = 0; e < 8; ++e) {
      int k = k0 + e;
      float v;
      if (cls < 10 && k < 100) v = w_out[(size_t)st * 1000 + k * 10 + cls];
      else if (k == 127)       v = (cls < 10) ? b_out[st * 10 + cls] : -60000.f;
      else                     v = 0.f;
      f[e] = v;
    }
    split8w(f, hi, lo);
    char* dst = ws + OFF_WO + (size_t)st * CHUNK + (size_t)(kb * 2) * 1024 + lane * 16;
    *(uint4*)dst = hi;
    *(uint4*)(dst + 1024) = lo;
    return;
  }
  grp -= 24;
  if (grp < 2) {  // BIN: p1 epilogue bias (128 f32), bin[127] = 1.0
    int i = grp * 64 + lane;
    ((float*)(ws + OFF_BIN))[i] = (i < 100) ? b_in[i] : (i == 127 ? 1.f : 0.f);
  }
}

// ---------------------------------------------------------------------------
// p1: h1 = relu(x @ w_in + b_in) -> fragment-major h image in ws.
// 512 blocks x 512 thr; wave = 16 rows (l15) x 128 feats (mf loop).
// x loads: lane (l15,g) reads f4v @ g*4 and @ 16+g*4 -> each instruction is
// 16 full 64B lines, each line requested once. 3-step x prefetch.
// ---------------------------------------------------------------------------
#define P1_SMEM (3 * CHUNK)  // 49152 -> 2 blocks/CU, all 512 blocks resident

__global__ __launch_bounds__(512, 4) void p1_k(const float* __restrict__ x,
                                               char* __restrict__ ws) {
  extern __shared__ __align__(16) char sm[];
  const int tid = threadIdx.x;
  const int lane = tid & 63, wid = tid >> 6;
  const int l15 = lane & 15, g = lane >> 4;
  const int tile = blockIdx.x;  // 128 rows
  const char* w1g = ws + OFF_W1;
  const float* xr = x + (size_t)(tile * 128 + wid * 16 + l15) * 3072;

  f4v xP[2], xQ[2], xR[2];
  // prologue FIFO order: c0(2), x0(2), c1(2), x1(2), x2(2)
  stage2(w1g, sm, tid);
  __builtin_amdgcn_sched_barrier(0);
  xP[0] = ntld4(xr + g * 4);      xP[1] = ntld4(xr + 16 + g * 4);
  __builtin_amdgcn_sched_barrier(0);
  stage2(w1g + CHUNK, sm + CHUNK, tid);
  __builtin_amdgcn_sched_barrier(0);
  xQ[0] = ntld4(xr + 32 + g * 4); xQ[1] = ntld4(xr + 48 + g * 4);
  __builtin_amdgcn_sched_barrier(0);
  xR[0] = ntld4(xr + 64 + g * 4); xR[1] = ntld4(xr + 80 + g * 4);
  __builtin_amdgcn_sched_barrier(0);

  f4v acc[8] = {};
  const int abase = lane * 16;

  // steady FIFO at top(s): [x(s)2, c(s)2, x(s+1)2, c(s+1)2, x(s+2)2] -> vmcnt(6)
  auto step = [&](int s, f4v (&xa)[2]) {
    if (s <= 93)      asm volatile("s_waitcnt vmcnt(6)" ::: "memory");
    else if (s == 94) asm volatile("s_waitcnt vmcnt(4)" ::: "memory");
    else              asm volatile("s_waitcnt vmcnt(0)" ::: "memory");
    __builtin_amdgcn_s_barrier();
    asm volatile("" ::: "memory");

    h8v bhi, blo;
    cvt8(xa[0], xa[1], bhi, blo);   // kappa-ordered: [q0 of k16a | q of k16b]
    // issue order matters: c(s+2) BEFORE x(s+3) (FIFO drain pairing)
    if (s + 2 < 96) stage2(w1g + (size_t)(s + 2) * CHUNK, sm + ((s + 2) % 3) * CHUNK, tid);
    __builtin_amdgcn_sched_barrier(0);
    if (s + 3 < 96) {
      const int o = (s + 3) * 32 + g * 4;
      xa[0] = ntld4(xr + o); xa[1] = ntld4(xr + o + 16);
    }
    __builtin_amdgcn_sched_barrier(0);

    const char* ab = sm + (s % 3) * CHUNK + abase;
#pragma unroll
    for (int mf = 0; mf < 8; ++mf) {
      h8v ahi = *(const h8v*)(ab + mf * 2048);
      h8v alo = *(const h8v*)(ab + mf * 2048 + 1024);
      acc[mf] = __builtin_amdgcn_mfma_f32_16x16x32_f16(ahi, bhi, acc[mf], 0, 0, 0);
      acc[mf] = __builtin_amdgcn_mfma_f32_16x16x32_f16(ahi, blo, acc[mf], 0, 0, 0);
      acc[mf] = __builtin_amdgcn_mfma_f32_16x16x32_f16(alo, bhi, acc[mf], 0, 0, 0);
    }
  };

#pragma unroll 1
  for (int s3 = 0; s3 < 96; s3 += 3) {
    step(s3, xP);
    step(s3 + 1, xQ);
    step(s3 + 2, xR);
  }

  // epilogue: bias + relu + split -> h frags (16x16 C/D: col=l15=row,
  // feature = mf*16 + g*4 + q).
  const float* bp = (const float*)(ws + OFF_BIN);
  const int rt = wid >> 1;
  const int l31 = (wid & 1) * 16 + l15;
  char* hb = ws + OFF_H1 + (size_t)tile * 65536;
#pragma unroll
  for (int mf = 0; mf < 8; ++mf) {
    f4v bi = *(const f4v*)(bp + mf * 16 + g * 4);
    f4v v = acc[mf] + bi;
    v[0] = fmaxf(v[0], 0.f); v[1] = fmaxf(v[1], 0.f);
    v[2] = fmaxf(v[2], 0.f); v[3] = fmaxf(v[3], 0.f);
    uint2 hi, lo;
    split4s(v, hi, lo);
    // B-frag slot: kblk=mf, g'=(g>>1), e=(g&1)*4+q
    char* dst = hb + (size_t)(rt * 8 + mf) * 2048 + (g >> 1) * 512 + l31 * 16 + (g & 1) * 8;
    *(uint2*)dst = hi;
    *(uint2*)(dst + 1024) = lo;
  }
}

// ---------------------------------------------------------------------------
// p2: cascade + heads + early-exit select (unchanged from round 9).
// ---------------------------------------------------------------------------
#define P2_SMEM (65536 + 3 * CHUNK)  // 114688

__global__ __launch_bounds__(512, 2) void p2_k(char* __restrict__ ws,
                                               float* __restrict__ out) {
  extern __shared__ __align__(16) char sm[];
  char* hsm = sm;             // h frags, 64KB
  char* wsm = sm + 65536;     // 3 chunk bufs
  const int tid = threadIdx.x;
  const int lane = tid & 63, wid = tid >> 6;
  const int mr = wid & 1, rt = wid >> 1;
  const int l31 = lane & 31, gg = lane >> 5;
  const int tile = blockIdx.x;

  {  // prologue DMA: h tile (8 loads) + items 0,1
    const char* hg = ws + OFF_H1 + (size_t)tile * 65536;
#pragma unroll
    for (int i = 0; i < 8; ++i)
      lds_cp16(hg + i * 8192 + tid * 16, hsm + i * 8192 + tid * 16);
    __builtin_amdgcn_sched_barrier(0);
    stage2(ws + item_off(0), wsm, tid);
    stage2(ws + item_off(1), wsm + CHUNK, tid);
  }

  const f16v z16 = {};
  f16v a0 = {}, a1 = {};
  float s0[6], s1[6], s2[6];
  bool c0 = false, c1 = false;

  auto ring_top = [&](int i) {
    asm volatile("s_waitcnt vmcnt(2)" ::: "memory");
    __builtin_amdgcn_s_barrier();
    asm volatile("" ::: "memory");
    stage2(ws + item_off(i + 2), wsm + ((i + 2) % 3) * CHUNK, tid);
  };

  auto hidden = [&](int base) {
#pragma unroll
    for (int ss = 0; ss < 4; ++ss) {
      ring_top(base + ss);
      const char* wb = wsm + ((base + ss) % 3) * CHUNK + lane * 16;
      const char* hbp = hsm + rt * 16384 + ss * 4096 + lane * 16;
      h8v bh0 = *(const h8v*)(hbp);
      h8v bl0 = *(const h8v*)(hbp + 1024);
      h8v bh1 = *(const h8v*)(hbp + 2048);
      h8v bl1 = *(const h8v*)(hbp + 3072);
      const char* ab0 = wb + (mr * 2) * 4096;
      const char* ab1 = ab0 + 4096;
      h8v ah, al;
      ah = *(const h8v*)(ab0);        al = *(const h8v*)(ab0 + 1024);
      a0 = __builtin_amdgcn_mfma_f32_32x32x16_f16(ah, bh0, a0, 0, 0, 0);
      a0 = __builtin_amdgcn_mfma_f32_32x32x16_f16(ah, bl0, a0, 0, 0, 0);
      a0 = __builtin_amdgcn_mfma_f32_32x32x16_f16(al, bh0, a0, 0, 0, 0);
      ah = *(const h8v*)(ab0 + 2048); al = *(const h8v*)(ab0 + 3072);
      a0 = __builtin_amdgcn_mfma_f32_32x32x16_f16(ah, bh1, a0, 0, 0, 0);
      a0 = __builtin_amdgcn_mfma_f32_32x32x16_f16(ah, bl1, a0, 0, 0, 0);
      a0 = __builtin_amdgcn_mfma_f32_32x32x16_f16(al, bh1, a0, 0, 0, 0);
      ah = *(const h8v*)(ab1);        al = *(const h8v*)(ab1 + 1024);
      a1 = __builtin_amdgcn_mfma_f32_32x32x16_f16(ah, bh0, a1, 0, 0, 0);
      a1 = __builtin_amdgcn_mfma_f32_32x32x16_f16(ah, bl0, a1, 0, 0, 0);
      a1 = __builtin_amdgcn_mfma_f32_32x32x16_f16(al, bh0, a1, 0, 0, 0);
      ah = *(const h8v*)(ab1 + 2048); al = *(const h8v*)(ab1 + 3072);
      a1 = __builtin_amdgcn_mfma_f32_32x32x16_f16(ah, bh1, a1, 0, 0, 0);
      a1 = __builtin_amdgcn_mfma_f32_32x32x16_f16(ah, bl1, a1, 0, 0, 0);
      a1 = __builtin_amdgcn_mfma_f32_32x32x16_f16(al, bh1, a1, 0, 0, 0);
    }
    __builtin_amdgcn_s_barrier();
    asm volatile("" ::: "memory");
#pragma unroll
    for (int fi = 0; fi < 2; ++fi) {
      const int ftb = mr * 2 + fi;
#pragma unroll
      for (int q = 0; q < 4; ++q) {
        f4v v = fi ? f4v{a1[4 * q], a1[4 * q + 1], a1[4 * q + 2], a1[4 * q + 3]}
                   : f4v{a0[4 * q], a0[4 * q + 1], a0[4 * q + 2], a0[4 * q + 3]};
        v[0] = fmaxf(v[0], 0.f); v[1] = fmaxf(v[1], 0.f);
        v[2] = fmaxf(v[2], 0.f); v[3] = fmaxf(v[3], 0.f);
        uint2 hi, lo;
        split4s(v, hi, lo);
        const int kblk = ftb * 2 + (q >> 1);
        char* dst = hsm + (size_t)((rt * 8 + kblk) * 2) * 1024 + ((q & 1) * 32 + l31) * 16 + gg * 8;
        *(uint2*)dst = hi;
        *(uint2*)(dst + 1024) = lo;
      }
    }
    asm volatile("s_waitcnt lgkmcnt(0)" ::: "memory");
    __builtin_amdgcn_s_barrier();
    asm volatile("" ::: "memory");
    a0 = z16;
    a1 = z16;
  };

  auto wstage = [&](int i, float (&sv)[6], bool* cb) {
    ring_top(i);
    const char* wb = wsm + (i % 3) * CHUNK + lane * 16;
    if (mr == 0) {
      f16v oa = {};
#pragma unroll
      for (int kb = 0; kb < 8; ++kb) {
        h8v ah = *(const h8v*)(wb + kb * 2048);
        h8v al = *(const h8v*)(wb + kb * 2048 + 1024);
        const char* hbp = hsm + rt * 16384 + kb * 2048 + lane * 16;
        h8v bh = *(const h8v*)(hbp);
        h8v bl = *(const h8v*)(hbp + 1024);
        oa = __builtin_amdgcn_mfma_f32_32x32x16_f16(ah, bh, oa, 0, 0, 0);
        oa = __builtin_amdgcn_mfma_f32_32x32x16_f16(ah, bl, oa, 0, 0, 0);
        oa = __builtin_amdgcn_mfma_f32_32x32x16_f16(al, bh, oa, 0, 0, 0);
      }
      float m = oa[0];
#pragma unroll
      for (int r = 1; r < 16; ++r) m = fmaxf(m, oa[r]);  // pads = -60000
      m = fmaxf(m, __shfl_xor(m, 32, 64));
      if (cb) *cb = (m > 0.5f);
      sv[0] = oa[0]; sv[1] = oa[1]; sv[2] = oa[2];
      sv[3] = oa[3]; sv[4] = oa[4]; sv[5] = oa[5];
    }
  };

  hidden(0); hidden(4); hidden(8); hidden(12);
  wstage(16, s0, &c0);
  hidden(17); hidden(21); hidden(25); hidden(29); hidden(33);
  wstage(37, s1, &c1);
  hidden(38); hidden(42); hidden(46); hidden(50); hidden(54);
  wstage(58, s2, nullptr);

  if (mr == 0) {
    float r[6];
#pragma unroll
    for (int j = 0; j < 6; ++j) r[j] = c0 ? s0[j] : (c1 ? s1[j] : s2[j]);
    float* dp = out + (size_t)(tile * 128 + rt * 32 + l31) * 10;
    if (gg == 0) {  // classes 0-3, 8-9
      *(float2*)(dp)     = make_float2(r[0], r[1]);
      *(float2*)(dp + 2) = make_float2(r[2], r[3]);
      *(float2*)(dp + 8) = make_float2(r[4], r[5]);
    } else {        // classes 4-7
      *(float2*)(dp + 4) = make_float2(r[0], r[1]);
      *(float2*)(dp + 6) = make_float2(r[2], r[3]);
    }
  }
}

// ---------------------------------------------------------------------------
extern "C" void kernel_launch(void* const* d_in, const int* in_sizes, int n_in,
                              void* d_out, int out_size, void* d_ws, size_t ws_size,
                              hipStream_t stream) {
  (void)in_sizes; (void)n_in; (void)out_size; (void)ws_size;
  const float* x     = (const float*)d_in[0];
  const float* w_in  = (const float*)d_in[1];
  const float* b_in  = (const float*)d_in[2];
  const float* w_hid = (const float*)d_in[3];
  const float* b_hid = (const float*)d_in[4];
  const float* w_out = (const float*)d_in[5];
  const float* b_out = (const float*)d_in[6];
  float* out = (float*)d_out;
  char* ws = (char*)d_ws;

  (void)hipFuncSetAttribute((const void*)p1_k,
                            hipFuncAttributeMaxDynamicSharedMemorySize, P1_SMEM);
  (void)hipFuncSetAttribute((const void*)p2_k,
                            hipFuncAttributeMaxDynamicSharedMemorySize, P2_SMEM);

  prep_k<<<311, 256, 0, stream>>>(w_in, b_in, w_hid, b_hid, w_out, b_out, ws);
  p1_k<<<512, 512, P1_SMEM, stream>>>(x, ws);
  p2_k<<<512, 512, P2_SMEM, stream>>>(ws, out);
}

// Round 11
// 307.427 us; speedup vs baseline: 3.3603x; 1.0676x over previous
//
#include <hip/hip_runtime.h>

// ---------------------------------------------------------------------------
// Cascade MLP, MI355X. fp16 hi/lo split GEMMs (3 passes, fp32 accum).
// FRAGMENT-MAJOR layouts: weight/h images are raw MFMA fragments (64 lanes x
// 16B = 1KB); every ds_read_b128 lane-linear -> zero bank conflicts
// (verified r9: SQ_LDS_BANK_CONFLICT 2.8e7 -> 0).
// p1 uses 16x16x32 with the kappa k-permutation so each x-load instruction
// covers 16 full 64B lines (verified r10: p1 940 -> ~235us).
// Round-11: p1 re-tiled to 256 blocks x 1024 thr x 256 rows. Rationale: p1's
// per-CU VMEM traffic was 50% weight re-staging (32KB x + 32KB W per step per
// CU at 128-row blocks); 256-row blocks halve the W share (48KB/step) ->
// predicted ~180-195us. Staging = 1x16B/thread, steady vmcnt(5).
// p2 (32x32 fragment-major cascade, bias folded via h[127]=1): unchanged.
// ---------------------------------------------------------------------------

typedef __fp16 h2   __attribute__((ext_vector_type(2)));
typedef __fp16 h8v  __attribute__((ext_vector_type(8)));
typedef float  f4v  __attribute__((ext_vector_type(4)));
typedef float  f16v __attribute__((ext_vector_type(16)));

#define CHUNK 16384   // one staged unit: 16 fragments x 1KB

static constexpr unsigned OFF_W1  = 0;                       // 96 chunks
static constexpr unsigned OFF_WH  = 96u * CHUNK;             // 1572864, 56 chunks
static constexpr unsigned OFF_WO  = OFF_WH + 56u * CHUNK;    // 2490368, 3 chunks
static constexpr unsigned OFF_BIN = OFF_WO + 3u * CHUNK;     // 2539520, 128 f32
static constexpr unsigned OFF_H1  = OFF_BIN + 512;           // 2540032, 512 x 64KB

__device__ __forceinline__ unsigned bc2(h2 v) { return __builtin_bit_cast(unsigned, v); }

__device__ __forceinline__ f4v ntld4(const float* p) {
  return __builtin_nontemporal_load((const f4v*)p);
}

__device__ __forceinline__ void lds_cp16(const char* g, char* l) {
  __builtin_amdgcn_global_load_lds(
      (const __attribute__((address_space(1))) void*)g,
      (__attribute__((address_space(3))) void*)l, 16, 0, 0);
}

// stage one 16KB chunk: 1024 thr x 16B (p1) or 512 thr x 2 x 16B (p2)
__device__ __forceinline__ void stage1(const char* g, char* l, int tid) {
  lds_cp16(g + tid * 16, l + tid * 16);
}
__device__ __forceinline__ void stage2(const char* g, char* l, int tid) {
  lds_cp16(g + tid * 16, l + tid * 16);
  lds_cp16(g + 8192 + tid * 16, l + 8192 + tid * 16);
}

// 8 fp32 (two f4v) -> hi/lo h8v fragments (element order a0..a3, b0..b3)
__device__ __forceinline__ void cvt8(f4v a, f4v b, h8v& hi, h8v& lo) {
  h2 h0 = __builtin_amdgcn_cvt_pkrtz(a[0], a[1]);
  h2 h1 = __builtin_amdgcn_cvt_pkrtz(a[2], a[3]);
  h2 h2_ = __builtin_amdgcn_cvt_pkrtz(b[0], b[1]);
  h2 h3 = __builtin_amdgcn_cvt_pkrtz(b[2], b[3]);
  h2 l0 = __builtin_amdgcn_cvt_pkrtz(a[0] - (float)h0[0], a[1] - (float)h0[1]);
  h2 l1 = __builtin_amdgcn_cvt_pkrtz(a[2] - (float)h1[0], a[3] - (float)h1[1]);
  h2 l2 = __builtin_amdgcn_cvt_pkrtz(b[0] - (float)h2_[0], b[1] - (float)h2_[1]);
  h2 l3 = __builtin_amdgcn_cvt_pkrtz(b[2] - (float)h3[0], b[3] - (float)h3[1]);
  hi = h8v{h0[0], h0[1], h1[0], h1[1], h2_[0], h2_[1], h3[0], h3[1]};
  lo = h8v{l0[0], l0[1], l1[0], l1[1], l2[0], l2[1], l3[0], l3[1]};
}

// relu'd f4v -> hi 8B + lo 8B
__device__ __forceinline__ void split4s(f4v v, uint2& hi, uint2& lo) {
  h2 a = __builtin_amdgcn_cvt_pkrtz(v[0], v[1]);
  h2 b = __builtin_amdgcn_cvt_pkrtz(v[2], v[3]);
  h2 c = __builtin_amdgcn_cvt_pkrtz(v[0] - (float)a[0], v[1] - (float)a[1]);
  h2 d = __builtin_amdgcn_cvt_pkrtz(v[2] - (float)b[0], v[3] - (float)b[1]);
  hi = make_uint2(bc2(a), bc2(b));
  lo = make_uint2(bc2(c), bc2(d));
}

__device__ __forceinline__ void split8w(const float* f, uint4& hi, uint4& lo) {
  h2 h0 = __builtin_amdgcn_cvt_pkrtz(f[0], f[1]);
  h2 h1 = __builtin_amdgcn_cvt_pkrtz(f[2], f[3]);
  h2 h2_ = __builtin_amdgcn_cvt_pkrtz(f[4], f[5]);
  h2 h3 = __builtin_amdgcn_cvt_pkrtz(f[6], f[7]);
  h2 l0 = __builtin_amdgcn_cvt_pkrtz(f[0] - (float)h0[0], f[1] - (float)h0[1]);
  h2 l1 = __builtin_amdgcn_cvt_pkrtz(f[2] - (float)h1[0], f[3] - (float)h1[1]);
  h2 l2 = __builtin_amdgcn_cvt_pkrtz(f[4] - (float)h2_[0], f[5] - (float)h2_[1]);
  h2 l3 = __builtin_amdgcn_cvt_pkrtz(f[6] - (float)h3[0], f[7] - (float)h3[1]);
  hi = make_uint4(bc2(h0), bc2(h1), bc2(h2_), bc2(h3));
  lo = make_uint4(bc2(l0), bc2(l1), bc2(l2), bc2(l3));
}

// flat items: L0-3=0..15, head0=16, L4-8=17..36, head1=37, L9-13=38..57, head2=58
__device__ __forceinline__ unsigned item_off(int it) {
  if (it >= 58) return OFF_WO + 2u * CHUNK;   // 58 + dummy tails
  if (it == 16) return OFF_WO;
  if (it == 37) return OFF_WO + CHUNK;
  int j = it - (it > 16 ? 1 : 0) - (it > 37 ? 1 : 0);
  return OFF_WH + (unsigned)j * CHUNK;
}

// ---------------------------------------------------------------------------
// prep: fragment-major images. 64-lane group = one fragment pair (hi+lo).
// ---------------------------------------------------------------------------
__global__ __launch_bounds__(256) void prep_k(
    const float* __restrict__ w_in, const float* __restrict__ b_in,
    const float* __restrict__ w_hid, const float* __restrict__ b_hid,
    const float* __restrict__ w_out, const float* __restrict__ b_out,
    char* __restrict__ ws) {
  int idx = blockIdx.x * 256 + threadIdx.x;
  int lane = idx & 63;
  int grp = idx >> 6;
  float f[8];
  uint4 hi, lo;
  if (grp < 768) {  // W1: c(96) x mf(8) 16x16x32 A-frags, kappa k-perm
    int mf = grp & 7, c = grp >> 3;
    int feat = mf * 16 + (lane & 15);
    int g = lane >> 4;
    int kb = c * 32 + g * 4;
#pragma unroll
    for (int e = 0; e < 8; ++e) {
      int k = kb + (e < 4 ? e : 12 + e);   // kappa(g,e): e>=4 -> +16
      f[e] = (feat < 100) ? w_in[(size_t)k * 100 + feat] : 0.f;
    }
    split8w(f, hi, lo);
    char* dst = ws + OFF_W1 + (size_t)c * CHUNK + (size_t)mf * 2048 + lane * 16;
    *(uint4*)dst = hi;
    *(uint4*)(dst + 1024) = lo;
    return;
  }
  grp -= 768;
  if (grp < 448) {  // WH: ch(56 = L*4+s) x ft(4) x j(2), 32x32 frags; bias @k=127
    int j = grp & 1, ft = (grp >> 1) & 3, ch = grp >> 3;
    int L = ch >> 2, s = ch & 3;
    int feat = ft * 32 + (lane & 31);
    int k0 = s * 32 + j * 16 + (lane >> 5) * 8;
#pragma unroll
    for (int e = 0; e < 8; ++e) {
      int k = k0 + e;
      float v;
      if (k < 100 && feat < 100)  v = w_hid[(size_t)L * 10000 + k * 100 + feat];
      else if (k == 127)          v = (feat < 100) ? b_hid[L * 100 + feat]
                                                   : (feat == 127 ? 1.f : 0.f);
      else                        v = 0.f;
      f[e] = v;
    }
    split8w(f, hi, lo);
    char* dst = ws + OFF_WH + (size_t)ch * CHUNK + (size_t)((ft * 2 + j) * 2) * 1024 + lane * 16;
    *(uint4*)dst = hi;
    *(uint4*)(dst + 1024) = lo;
    return;
  }
  grp -= 448;
  if (grp < 24) {  // WO: st(3) x kblk(8); bias row k=127, pad classes -60000
    int kb = grp & 7, st = grp >> 3;
    int cls = lane & 31;
    int k0 = kb * 16 + (lane >> 5) * 8;
#pragma unroll
    for (int e = 0; e < 8; ++e) {
      int k = k0 + e;
      float v;
      if (cls < 10 && k < 100) v = w_out[(size_t)st * 1000 + k * 10 + cls];
      else if (k == 127)       v = (cls < 10) ? b_out[st * 10 + cls] : -60000.f;
      else                     v = 0.f;
      f[e] = v;
    }
    split8w(f, hi, lo);
    char* dst = ws + OFF_WO + (size_t)st * CHUNK + (size_t)(kb * 2) * 1024 + lane * 16;
    *(uint4*)dst = hi;
    *(uint4*)(dst + 1024) = lo;
    return;
  }
  grp -= 24;
  if (grp < 2) {  // BIN: p1 epilogue bias (128 f32), bin[127] = 1.0
    int i = grp * 64 + lane;
    ((float*)(ws + OFF_BIN))[i] = (i < 100) ? b_in[i] : (i == 127 ? 1.f : 0.f);
  }
}

// ---------------------------------------------------------------------------
// p1: h1 = relu(x @ w_in + b_in) -> fragment-major h image in ws.
// 256 blocks x 1024 thr (16 waves x 16 rows = 256 rows/block, 1 block/CU).
// x loads: lane (l15,g) reads f4v @ g*4 and @ 16+g*4 -> each instruction
// covers 16 full 64B lines. W-staging = 16KB/step/block against 32KB of x
// (was 1:1 at 128-row blocks -> the round-10 VMEM-pipe bottleneck).
// ---------------------------------------------------------------------------
#define P1_SMEM (3 * CHUNK)  // 49152

__global__ __launch_bounds__(1024, 4) void p1_k(const float* __restrict__ x,
                                                char* __restrict__ ws) {
  extern __shared__ __align__(16) char sm[];
  const int tid = threadIdx.x;
  const int lane = tid & 63, wid = tid >> 6;   // wid 0..15
  const int l15 = lane & 15, g = lane >> 4;
  const int tile = blockIdx.x;  // 256 rows
  const char* w1g = ws + OFF_W1;
  const float* xr = x + (size_t)(tile * 256 + wid * 16 + l15) * 3072;

  f4v xP[2], xQ[2], xR[2];
  // prologue FIFO order: c0(1), x0(2), c1(1), x1(2), x2(2)  -> 8 outstanding
  stage1(w1g, sm, tid);
  __builtin_amdgcn_sched_barrier(0);
  xP[0] = ntld4(xr + g * 4);      xP[1] = ntld4(xr + 16 + g * 4);
  __builtin_amdgcn_sched_barrier(0);
  stage1(w1g + CHUNK, sm + CHUNK, tid);
  __builtin_amdgcn_sched_barrier(0);
  xQ[0] = ntld4(xr + 32 + g * 4); xQ[1] = ntld4(xr + 48 + g * 4);
  __builtin_amdgcn_sched_barrier(0);
  xR[0] = ntld4(xr + 64 + g * 4); xR[1] = ntld4(xr + 80 + g * 4);
  __builtin_amdgcn_sched_barrier(0);

  f4v acc[8] = {};
  const int abase = lane * 16;

  // steady FIFO at top(s): [c(s)1, x(s)2, c(s+1)1, x(s+1)2, x(s+2)2] -> vmcnt(5)
  auto step = [&](int s, f4v (&xa)[2]) {
    if (s <= 93)      asm volatile("s_waitcnt vmcnt(5)" ::: "memory");
    else if (s == 94) asm volatile("s_waitcnt vmcnt(3)" ::: "memory");
    else              asm volatile("s_waitcnt vmcnt(0)" ::: "memory");
    __builtin_amdgcn_s_barrier();
    asm volatile("" ::: "memory");

    h8v bhi, blo;
    cvt8(xa[0], xa[1], bhi, blo);   // kappa-ordered
    // issue order: c(s+2) BEFORE x(s+3) (FIFO drain pairing)
    if (s + 2 < 96) stage1(w1g + (size_t)(s + 2) * CHUNK, sm + ((s + 2) % 3) * CHUNK, tid);
    __builtin_amdgcn_sched_barrier(0);
    if (s + 3 < 96) {
      const int o = (s + 3) * 32 + g * 4;
      xa[0] = ntld4(xr + o); xa[1] = ntld4(xr + o + 16);
    }
    __builtin_amdgcn_sched_barrier(0);

    const char* ab = sm + (s % 3) * CHUNK + abase;
#pragma unroll
    for (int mf = 0; mf < 8; ++mf) {
      h8v ahi = *(const h8v*)(ab + mf * 2048);
      h8v alo = *(const h8v*)(ab + mf * 2048 + 1024);
      acc[mf] = __builtin_amdgcn_mfma_f32_16x16x32_f16(ahi, bhi, acc[mf], 0, 0, 0);
      acc[mf] = __builtin_amdgcn_mfma_f32_16x16x32_f16(ahi, blo, acc[mf], 0, 0, 0);
      acc[mf] = __builtin_amdgcn_mfma_f32_16x16x32_f16(alo, bhi, acc[mf], 0, 0, 0);
    }
  };

#pragma unroll 1
  for (int s3 = 0; s3 < 96; s3 += 3) {
    step(s3, xP);
    step(s3 + 1, xQ);
    step(s3 + 2, xR);
  }

  // epilogue: bias + relu + split -> h frags (16x16 C/D: col=l15=row,
  // feature = mf*16 + g*4 + q). Global row R = tile*256 + wid*16 + l15.
  const float* bp = (const float*)(ws + OFF_BIN);
  const int p2tile = tile * 2 + (wid >> 3);   // R >> 7
  const int rt = (wid >> 1) & 3;              // (R >> 5) & 3
  const int l31 = (wid & 1) * 16 + l15;       // R & 31
  char* hb = ws + OFF_H1 + (size_t)p2tile * 65536;
#pragma unroll
  for (int mf = 0; mf < 8; ++mf) {
    f4v bi = *(const f4v*)(bp + mf * 16 + g * 4);
    f4v v = acc[mf] + bi;
    v[0] = fmaxf(v[0], 0.f); v[1] = fmaxf(v[1], 0.f);
    v[2] = fmaxf(v[2], 0.f); v[3] = fmaxf(v[3], 0.f);
    uint2 hi, lo;
    split4s(v, hi, lo);
    // B-frag slot: kblk=mf, g'=(g>>1), e=(g&1)*4+q
    char* dst = hb + (size_t)(rt * 8 + mf) * 2048 + (g >> 1) * 512 + l31 * 16 + (g & 1) * 8;
    *(uint2*)dst = hi;
    *(uint2*)(dst + 1024) = lo;
  }
}

// ---------------------------------------------------------------------------
// p2: cascade + heads + early-exit select (unchanged from round 10).
// ---------------------------------------------------------------------------
#define P2_SMEM (65536 + 3 * CHUNK)  // 114688

__global__ __launch_bounds__(512, 2) void p2_k(char* __restrict__ ws,
                                               float* __restrict__ out) {
  extern __shared__ __align__(16) char sm[];
  char* hsm = sm;             // h frags, 64KB
  char* wsm = sm + 65536;     // 3 chunk bufs
  const int tid = threadIdx.x;
  const int lane = tid & 63, wid = tid >> 6;
  const int mr = wid & 1, rt = wid >> 1;
  const int l31 = lane & 31, gg = lane >> 5;
  const int tile = blockIdx.x;

  {  // prologue DMA: h tile (8 loads) + items 0,1
    const char* hg = ws + OFF_H1 + (size_t)tile * 65536;
#pragma unroll
    for (int i = 0; i < 8; ++i)
      lds_cp16(hg + i * 8192 + tid * 16, hsm + i * 8192 + tid * 16);
    __builtin_amdgcn_sched_barrier(0);
    stage2(ws + item_off(0), wsm, tid);
    stage2(ws + item_off(1), wsm + CHUNK, tid);
  }

  const f16v z16 = {};
  f16v a0 = {}, a1 = {};
  float s0[6], s1[6], s2[6];
  bool c0 = false, c1 = false;

  auto ring_top = [&](int i) {
    asm volatile("s_waitcnt vmcnt(2)" ::: "memory");
    __builtin_amdgcn_s_barrier();
    asm volatile("" ::: "memory");
    stage2(ws + item_off(i + 2), wsm + ((i + 2) % 3) * CHUNK, tid);
  };

  auto hidden = [&](int base) {
#pragma unroll
    for (int ss = 0; ss < 4; ++ss) {
      ring_top(base + ss);
      const char* wb = wsm + ((base + ss) % 3) * CHUNK + lane * 16;
      const char* hbp = hsm + rt * 16384 + ss * 4096 + lane * 16;
      h8v bh0 = *(const h8v*)(hbp);
      h8v bl0 = *(const h8v*)(hbp + 1024);
      h8v bh1 = *(const h8v*)(hbp + 2048);
      h8v bl1 = *(const h8v*)(hbp + 3072);
      const char* ab0 = wb + (mr * 2) * 4096;
      const char* ab1 = ab0 + 4096;
      h8v ah, al;
      ah = *(const h8v*)(ab0);        al = *(const h8v*)(ab0 + 1024);
      a0 = __builtin_amdgcn_mfma_f32_32x32x16_f16(ah, bh0, a0, 0, 0, 0);
      a0 = __builtin_amdgcn_mfma_f32_32x32x16_f16(ah, bl0, a0, 0, 0, 0);
      a0 = __builtin_amdgcn_mfma_f32_32x32x16_f16(al, bh0, a0, 0, 0, 0);
      ah = *(const h8v*)(ab0 + 2048); al = *(const h8v*)(ab0 + 3072);
      a0 = __builtin_amdgcn_mfma_f32_32x32x16_f16(ah, bh1, a0, 0, 0, 0);
      a0 = __builtin_amdgcn_mfma_f32_32x32x16_f16(ah, bl1, a0, 0, 0, 0);
      a0 = __builtin_amdgcn_mfma_f32_32x32x16_f16(al, bh1, a0, 0, 0, 0);
      ah = *(const h8v*)(ab1);        al = *(const h8v*)(ab1 + 1024);
      a1 = __builtin_amdgcn_mfma_f32_32x32x16_f16(ah, bh0, a1, 0, 0, 0);
      a1 = __builtin_amdgcn_mfma_f32_32x32x16_f16(ah, bl0, a1, 0, 0, 0);
      a1 = __builtin_amdgcn_mfma_f32_32x32x16_f16(al, bh0, a1, 0, 0, 0);
      ah = *(const h8v*)(ab1 + 2048); al = *(const h8v*)(ab1 + 3072);
      a1 = __builtin_amdgcn_mfma_f32_32x32x16_f16(ah, bh1, a1, 0, 0, 0);
      a1 = __builtin_amdgcn_mfma_f32_32x32x16_f16(ah, bl1, a1, 0, 0, 0);
      a1 = __builtin_amdgcn_mfma_f32_32x32x16_f16(al, bh1, a1, 0, 0, 0);
    }
    __builtin_amdgcn_s_barrier();
    asm volatile("" ::: "memory");
#pragma unroll
    for (int fi = 0; fi < 2; ++fi) {
      const int ftb = mr * 2 + fi;
#pragma unroll
      for (int q = 0; q < 4; ++q) {
        f4v v = fi ? f4v{a1[4 * q], a1[4 * q + 1], a1[4 * q + 2], a1[4 * q + 3]}
                   : f4v{a0[4 * q], a0[4 * q + 1], a0[4 * q + 2], a0[4 * q + 3]};
        v[0] = fmaxf(v[0], 0.f); v[1] = fmaxf(v[1], 0.f);
        v[2] = fmaxf(v[2], 0.f); v[3] = fmaxf(v[3], 0.f);
        uint2 hi, lo;
        split4s(v, hi, lo);
        const int kblk = ftb * 2 + (q >> 1);
        char* dst = hsm + (size_t)((rt * 8 + kblk) * 2) * 1024 + ((q & 1) * 32 + l31) * 16 + gg * 8;
        *(uint2*)dst = hi;
        *(uint2*)(dst + 1024) = lo;
      }
    }
    asm volatile("s_waitcnt lgkmcnt(0)" ::: "memory");
    __builtin_amdgcn_s_barrier();
    asm volatile("" ::: "memory");
    a0 = z16;
    a1 = z16;
  };

  auto wstage = [&](int i, float (&sv)[6], bool* cb) {
    ring_top(i);
    const char* wb = wsm + (i % 3) * CHUNK + lane * 16;
    if (mr == 0) {
      f16v oa = {};
#pragma unroll
      for (int kb = 0; kb < 8; ++kb) {
        h8v ah = *(const h8v*)(wb + kb * 2048);
        h8v al = *(const h8v*)(wb + kb * 2048 + 1024);
        const char* hbp = hsm + rt * 16384 + kb * 2048 + lane * 16;
        h8v bh = *(const h8v*)(hbp);
        h8v bl = *(const h8v*)(hbp + 1024);
        oa = __builtin_amdgcn_mfma_f32_32x32x16_f16(ah, bh, oa, 0, 0, 0);
        oa = __builtin_amdgcn_mfma_f32_32x32x16_f16(ah, bl, oa, 0, 0, 0);
        oa = __builtin_amdgcn_mfma_f32_32x32x16_f16(al, bh, oa, 0, 0, 0);
      }
      float m = oa[0];
#pragma unroll
      for (int r = 1; r < 16; ++r) m = fmaxf(m, oa[r]);  // pads = -60000
      m = fmaxf(m, __shfl_xor(m, 32, 64));
      if (cb) *cb = (m > 0.5f);
      sv[0] = oa[0]; sv[1] = oa[1]; sv[2] = oa[2];
      sv[3] = oa[3]; sv[4] = oa[4]; sv[5] = oa[5];
    }
  };

  hidden(0); hidden(4); hidden(8); hidden(12);
  wstage(16, s0, &c0);
  hidden(17); hidden(21); hidden(25); hidden(29); hidden(33);
  wstage(37, s1, &c1);
  hidden(38); hidden(42); hidden(46); hidden(50); hidden(54);
  wstage(58, s2, nullptr);

  if (mr == 0) {
    float r[6];
#pragma unroll
    for (int j = 0; j < 6; ++j) r[j] = c0 ? s0[j] : (c1 ? s1[j] : s2[j]);
    float* dp = out + (size_t)(tile * 128 + rt * 32 + l31) * 10;
    if (gg == 0) {  // classes 0-3, 8-9
      *(float2*)(dp)     = make_float2(r[0], r[1]);
      *(float2*)(dp + 2) = make_float2(r[2], r[3]);
      *(float2*)(dp + 8) = make_float2(r[4], r[5]);
    } else {        // classes 4-7
      *(float2*)(dp + 4) = make_float2(r[0], r[1]);
      *(float2*)(dp + 6) = make_float2(r[2], r[3]);
    }
  }
}

// ---------------------------------------------------------------------------
extern "C" void kernel_launch(void* const* d_in, const int* in_sizes, int n_in,
                              void* d_out, int out_size, void* d_ws, size_t ws_size,
                              hipStream_t stream) {
  (void)in_sizes; (void)n_in; (void)out_size; (void)ws_size;
  const float* x     = (const float*)d_in[0];
  const float* w_in  = (const float*)d_in[1];
  const float* b_in  = (const float*)d_in[2];
  const float* w_hid = (const float*)d_in[3];
  const float* b_hid = (const float*)d_in[4];
  const float* w_out = (const float*)d_in[5];
  const float* b_out = (const float*)d_in[6];
  float* out = (float*)d_out;
  char* ws = (char*)d_ws;

  (void)hipFuncSetAttribute((const void*)p1_k,
                            hipFuncAttributeMaxDynamicSharedMemorySize, P1_SMEM);
  (void)hipFuncSetAttribute((const void*)p2_k,
                            hipFuncAttributeMaxDynamicSharedMemorySize, P2_SMEM);

  prep_k<<<311, 256, 0, stream>>>(w_in, b_in, w_hid, b_hid, w_out, b_out, ws);
  p1_k<<<256, 1024, P1_SMEM, stream>>>(x, ws);
  p2_k<<<512, 512, P2_SMEM, stream>>>(ws, out);
}